// Round 1
// baseline (397.040 us; speedup 1.0000x reference)
//
#include <hip/hip_runtime.h>

// HXELoss: hierarchical cross-entropy over a balanced 8-ary tree, C=4096, L=4.
// Reduces to per-row softmax partial sums over nested index blocks of size
// 1/8/64/512/4096. Only logits (4 MiB), targets, and one weights row are read;
// the dense onehot tensors are never touched.

#define BATCH 256
#define NCLS 4096
#define LVLS 4

__global__ __launch_bounds__(256) void hxe_per_sample(
    const float* __restrict__ logits,
    const int*   __restrict__ tgt,      // (B, L) int32
    const float* __restrict__ weights,  // (C, L)
    float*       __restrict__ per_sample) // (B)
{
    const int b    = blockIdx.x;
    const int tid  = threadIdx.x;
    const int wave = tid >> 6;
    const int lane = tid & 63;
    const int t    = tgt[b * LVLS + (LVLS - 1)];

    const float4* row4 = (const float4*)(logits + (size_t)b * NCLS);

    // 16 elements per thread, coalesced float4 loads.
    float4 v[4];
#pragma unroll
    for (int k = 0; k < 4; ++k) v[k] = row4[k * 256 + tid];

    // ---- row max ----
    float m = -3.402823466e38f;
#pragma unroll
    for (int k = 0; k < 4; ++k)
        m = fmaxf(m, fmaxf(fmaxf(v[k].x, v[k].y), fmaxf(v[k].z, v[k].w)));
#pragma unroll
    for (int off = 32; off > 0; off >>= 1)
        m = fmaxf(m, __shfl_down(m, off, 64));

    __shared__ float wmax[4];
    __shared__ float wsum[4][5];
    if (lane == 0) wmax[wave] = m;
    __syncthreads();
    m = fmaxf(fmaxf(wmax[0], wmax[1]), fmaxf(wmax[2], wmax[3]));

    // ---- nested exp sums: s[4]=full Z, s[j]=block of size 8^j containing t ----
    float s[5] = {0.f, 0.f, 0.f, 0.f, 0.f};
#pragma unroll
    for (int k = 0; k < 4; ++k) {
        const int cbase = (k * 256 + tid) * 4;
        const float e0 = __expf(v[k].x - m);
        const float e1 = __expf(v[k].y - m);
        const float e2 = __expf(v[k].z - m);
        const float e3 = __expf(v[k].w - m);
        const float e[4] = {e0, e1, e2, e3};
        s[4] += (e0 + e1) + (e2 + e3);
        // All 4 elements of a float4 share the same >>3 (and coarser) block
        // only if cbase..cbase+3 lie in one 8-block — they do (4 | 8). So the
        // level-1..3 membership is uniform across the float4.
        if ((cbase >> 9) == (t >> 9)) {
            float q = (e0 + e1) + (e2 + e3);
            s[3] += q;
            if ((cbase >> 6) == (t >> 6)) {
                s[2] += q;
                if ((cbase >> 3) == (t >> 3)) {
                    s[1] += q;
                    if ((t & ~3) == cbase) s[0] += e[t & 3];
                }
            }
        }
    }

#pragma unroll
    for (int off = 32; off > 0; off >>= 1) {
#pragma unroll
        for (int j = 0; j < 5; ++j) s[j] += __shfl_down(s[j], off, 64);
    }
    if (lane == 0) {
#pragma unroll
        for (int j = 0; j < 5; ++j) wsum[wave][j] = s[j];
    }
    __syncthreads();

    if (tid == 0) {
        float S[5];
#pragma unroll
        for (int j = 0; j < 5; ++j)
            S[j] = (wsum[0][j] + wsum[1][j]) + (wsum[2][j] + wsum[3][j]);
        const float invZ = 1.0f / S[4];
        float loss = 0.f;
#pragma unroll
        for (int j = 0; j < LVLS; ++j) {
            const float num = S[j] * invZ;
            const float den = (j < LVLS - 1) ? S[j + 1] * invZ : 1.0f;
            const float w   = weights[t * LVLS + j];
            if (num != 0.0f) loss += w * (-logf(num / den));
        }
        per_sample[b] = loss;
    }
}

__global__ __launch_bounds__(256) void hxe_reduce(
    const float* __restrict__ per_sample, float* __restrict__ out)
{
    const int tid = threadIdx.x;
    float v = per_sample[tid];
#pragma unroll
    for (int off = 32; off > 0; off >>= 1)
        v += __shfl_down(v, off, 64);
    __shared__ float w[4];
    if ((tid & 63) == 0) w[tid >> 6] = v;
    __syncthreads();
    if (tid == 0)
        out[0] = ((w[0] + w[1]) + (w[2] + w[3])) * (1.0f / BATCH);
}

extern "C" void kernel_launch(void* const* d_in, const int* in_sizes, int n_in,
                              void* d_out, int out_size, void* d_ws, size_t ws_size,
                              hipStream_t stream) {
    const float* logits  = (const float*)d_in[0];
    const int*   tgt     = (const int*)d_in[1];   // int64 in ref -> int32 per harness
    const float* weights = (const float*)d_in[4]; // (C, L)
    float* per_sample = (float*)d_ws;             // 256 floats scratch
    float* out        = (float*)d_out;

    hxe_per_sample<<<BATCH, 256, 0, stream>>>(logits, tgt, weights, per_sample);
    hxe_reduce<<<1, 256, 0, stream>>>(per_sample, out);
}